// Round 2
// baseline (2935.848 us; speedup 1.0000x reference)
//
#include <hip/hip_runtime.h>
#include <hip/hip_bf16.h>

#define NN 50000
#define NE 800000
#define DH 128
#define NCLS 40
#define HOPS 30

// ---------------- graph build ----------------

__global__ void count_deg(const int* __restrict__ dst, int* __restrict__ cnt) {
    int e = blockIdx.x * blockDim.x + threadIdx.x;
    if (e < NE) atomicAdd(&cnt[dst[e]], 1);
}

__global__ void calc_dinv(const int* __restrict__ cnt, float* __restrict__ dinv) {
    int v = blockIdx.x * blockDim.x + threadIdx.x;
    if (v < NN) dinv[v] = rsqrtf((float)cnt[v] + 1.0f);  // +1 self-loop; deg>=1 always
}

// block-level inclusive scan (1024/block) -> exclusive per-element, block sums out
__global__ void scan1(const int* __restrict__ cnt, int* __restrict__ rowptr,
                      int* __restrict__ bsum) {
    __shared__ int s[1024];
    int t = threadIdx.x;
    int i = blockIdx.x * 1024 + t;
    int v = (i < NN) ? cnt[i] : 0;
    s[t] = v;
    __syncthreads();
    for (int off = 1; off < 1024; off <<= 1) {
        int add = (t >= off) ? s[t - off] : 0;
        __syncthreads();
        s[t] += add;
        __syncthreads();
    }
    if (i < NN) rowptr[i] = s[t] - v;  // exclusive within block
    if (t == 1023) bsum[blockIdx.x] = s[1023];
}

__global__ void scan2(int* __restrict__ bsum, int* __restrict__ rowptr, int nb) {
    if (blockIdx.x == 0 && threadIdx.x == 0) {
        int run = 0;
        for (int b = 0; b < nb; ++b) { int v = bsum[b]; bsum[b] = run; run += v; }
        rowptr[NN] = run;
    }
}

__global__ void scan3(int* __restrict__ rowptr, const int* __restrict__ bsum,
                      int* __restrict__ cursor) {
    int i = blockIdx.x * 1024 + threadIdx.x;
    if (i < NN) {
        int r = rowptr[i] + bsum[blockIdx.x];
        rowptr[i] = r;
        cursor[i] = r;
    }
}

__global__ void fill_csr(const int* __restrict__ src, const int* __restrict__ dst,
                         const float* __restrict__ dinv, int* __restrict__ cursor,
                         int* __restrict__ csr_src, float* __restrict__ csr_w) {
    int e = blockIdx.x * blockDim.x + threadIdx.x;
    if (e < NE) {
        int s = src[e], d = dst[e];
        int p = atomicAdd(&cursor[d], 1);
        csr_src[p] = s;
        csr_w[p] = dinv[s] * dinv[d];
    }
}

// ---------------- GEMMs (f32 vector ALU; no fp32 MFMA on CDNA4) ----------------

// C[n x 128] = relu?(A[n x 128] @ W[128 x 128] + bias)
template <bool RELU>
__global__ __launch_bounds__(256) void gemm128(const float* __restrict__ A,
                                               const float* __restrict__ W,
                                               const float* __restrict__ bias,
                                               float* __restrict__ C, int n) {
    __shared__ float xs[64 * 128];   // 32 KB
    __shared__ float ws[32 * 128];   // 16 KB
    const int t = threadIdx.x;
    const int row0 = blockIdx.x * 64;

    const float4* A4 = reinterpret_cast<const float4*>(A);
    float4* xs4 = reinterpret_cast<float4*>(xs);
    for (int i = t; i < 64 * 32; i += 256) {
        int r = i >> 5, c4 = i & 31;
        int gr = row0 + r;
        xs4[i] = (gr < n) ? A4[(size_t)gr * 32 + c4] : make_float4(0.f, 0.f, 0.f, 0.f);
    }

    float acc[8][4];
#pragma unroll
    for (int r = 0; r < 8; ++r)
#pragma unroll
        for (int j = 0; j < 4; ++j) acc[r][j] = 0.f;

    const int cb = (t & 31) * 4;   // col base 0..124
    const int rb = (t >> 5) * 8;   // row base 0..56
    const float4* W4 = reinterpret_cast<const float4*>(W);
    float4* ws4 = reinterpret_cast<float4*>(ws);

    for (int k0 = 0; k0 < 128; k0 += 32) {
        __syncthreads();  // xs ready (first iter) / ws reads done (later iters)
        for (int i = t; i < 32 * 32; i += 256)
            ws4[i] = W4[(size_t)(k0 + (i >> 5)) * 32 + (i & 31)];
        __syncthreads();
#pragma unroll
        for (int kk = 0; kk < 32; ++kk) {
            float4 wv = ws4[kk * 32 + (cb >> 2)];
#pragma unroll
            for (int r = 0; r < 8; ++r) {
                float xv = xs[(rb + r) * 128 + k0 + kk];
                acc[r][0] += xv * wv.x;
                acc[r][1] += xv * wv.y;
                acc[r][2] += xv * wv.z;
                acc[r][3] += xv * wv.w;
            }
        }
    }

    float4 bv = reinterpret_cast<const float4*>(bias)[cb >> 2];
#pragma unroll
    for (int r = 0; r < 8; ++r) {
        int gr = row0 + rb + r;
        if (gr < n) {
            float4 o;
            o.x = acc[r][0] + bv.x;
            o.y = acc[r][1] + bv.y;
            o.z = acc[r][2] + bv.z;
            o.w = acc[r][3] + bv.w;
            if (RELU) {
                o.x = fmaxf(o.x, 0.f); o.y = fmaxf(o.y, 0.f);
                o.z = fmaxf(o.z, 0.f); o.w = fmaxf(o.w, 0.f);
            }
            reinterpret_cast<float4*>(C)[(size_t)gr * 32 + (cb >> 2)] = o;
        }
    }
}

// C[n x 40] = A[n x 128] @ W[128 x 40] + bias
__global__ __launch_bounds__(256) void gemm40(const float* __restrict__ A,
                                              const float* __restrict__ W,
                                              const float* __restrict__ bias,
                                              float* __restrict__ C, int n) {
    __shared__ float xs[32 * 128];   // 16 KB
    __shared__ float wl[128 * 40];   // 20 KB
    __shared__ float bl[40];
    const int t = threadIdx.x;
    const int row0 = blockIdx.x * 32;

    const float4* A4 = reinterpret_cast<const float4*>(A);
    float4* xs4 = reinterpret_cast<float4*>(xs);
    for (int i = t; i < 32 * 32; i += 256) {
        int r = i >> 5, gr = row0 + r;
        xs4[i] = (gr < n) ? A4[(size_t)gr * 32 + (i & 31)] : make_float4(0.f, 0.f, 0.f, 0.f);
    }
    for (int i = t; i < 128 * 40; i += 256) wl[i] = W[i];
    if (t < 40) bl[t] = bias[t];
    __syncthreads();

    const int r = t >> 3;       // 0..31
    const int c0 = (t & 7) * 5; // 0..35
    float acc[5] = {0.f, 0.f, 0.f, 0.f, 0.f};
    for (int k = 0; k < 128; ++k) {
        float xv = xs[r * 128 + k];
#pragma unroll
        for (int j = 0; j < 5; ++j) acc[j] += xv * wl[k * 40 + c0 + j];
    }
    int gr = row0 + r;
    if (gr < n) {
#pragma unroll
        for (int j = 0; j < 5; ++j) C[(size_t)gr * 40 + c0 + j] = acc[j] + bl[c0 + j];
    }
}

// ---------------- propagation ----------------

__global__ __launch_bounds__(128) void prop128(const float* __restrict__ hin,
                                               float* __restrict__ hout,
                                               const int* __restrict__ rowptr,
                                               const int* __restrict__ csr_src,
                                               const float* __restrict__ csr_w,
                                               const float* __restrict__ dinv,
                                               int relu) {
    const int v = blockIdx.x;
    const int d = threadIdx.x;
    float dv = dinv[v];
    float acc = dv * dv * hin[(size_t)v * DH + d];
    const int beg = rowptr[v], end = rowptr[v + 1];
    for (int e = beg; e < end; ++e) {
        acc += csr_w[e] * hin[(size_t)csr_src[e] * DH + d];
    }
    if (relu) acc = fmaxf(acc, 0.f);
    hout[(size_t)v * DH + d] = acc;
}

__global__ __launch_bounds__(64) void prop40(const float* __restrict__ z,
                                             float* __restrict__ out,
                                             const int* __restrict__ rowptr,
                                             const int* __restrict__ csr_src,
                                             const float* __restrict__ csr_w,
                                             const float* __restrict__ dinv) {
    const int v = blockIdx.x;
    const int d = threadIdx.x;
    if (d >= NCLS) return;
    float dv = dinv[v];
    float acc = dv * dv * z[(size_t)v * NCLS + d];
    const int beg = rowptr[v], end = rowptr[v + 1];
    for (int e = beg; e < end; ++e) {
        acc += csr_w[e] * z[(size_t)csr_src[e] * NCLS + d];
    }
    out[(size_t)v * NCLS + d] = acc;
}

// ---------------- launch ----------------

extern "C" void kernel_launch(void* const* d_in, const int* in_sizes, int n_in,
                              void* d_out, int out_size, void* d_ws, size_t ws_size,
                              hipStream_t stream) {
    const float* x   = (const float*)d_in[0];
    const int* edge  = (const int*)d_in[1];
    const float* W1  = (const float*)d_in[2];
    const float* b1  = (const float*)d_in[3];
    const float* W2  = (const float*)d_in[4];
    const float* b2  = (const float*)d_in[5];
    const float* Wc  = (const float*)d_in[6];
    const float* bc  = (const float*)d_in[7];
    // d_in[8] = conv_time (=30), hardcoded as HOPS (host cannot read device mem under capture)
    const int* esrc = edge;
    const int* edst = edge + NE;
    float* out = (float*)d_out;

    // workspace carve-up (256B aligned)
    char* w = (char*)d_ws;
    auto alloc = [&](size_t bytes) { void* p = (void*)w; w += (bytes + 255) & ~(size_t)255; return p; };
    int*   cnt     = (int*)  alloc((size_t)NN * 4);
    float* dinv    = (float*)alloc((size_t)NN * 4);
    int*   rowptr  = (int*)  alloc((size_t)(NN + 1) * 4);
    int*   bsum    = (int*)  alloc(64 * 4);
    int*   cursor  = (int*)  alloc((size_t)NN * 4);
    int*   csr_src = (int*)  alloc((size_t)NE * 4);
    float* csr_w   = (float*)alloc((size_t)NE * 4);
    float* h0      = (float*)alloc((size_t)NN * DH * 4);
    float* h1      = (float*)alloc((size_t)NN * DH * 4);
    float* z       = (float*)alloc((size_t)NN * NCLS * 4);

    const int NB_SCAN = (NN + 1023) / 1024;  // 49

    hipMemsetAsync(cnt, 0, (size_t)NN * 4, stream);
    count_deg<<<(NE + 255) / 256, 256, 0, stream>>>(edst, cnt);
    calc_dinv<<<(NN + 255) / 256, 256, 0, stream>>>(cnt, dinv);
    scan1<<<NB_SCAN, 1024, 0, stream>>>(cnt, rowptr, bsum);
    scan2<<<1, 64, 0, stream>>>(bsum, rowptr, NB_SCAN);
    scan3<<<NB_SCAN, 1024, 0, stream>>>(rowptr, bsum, cursor);
    fill_csr<<<(NE + 255) / 256, 256, 0, stream>>>(esrc, edst, dinv, cursor, csr_src, csr_w);

    // h0 = relu(x @ W1 + b1)
    gemm128<true><<<(NN + 63) / 64, 256, 0, stream>>>(x, W1, b1, h0, NN);
    // h1 = h0 @ W2 + b2
    gemm128<false><<<(NN + 63) / 64, 256, 0, stream>>>(h0, W2, b2, h1, NN);

    // 30 propagation hops; relu on the last
    float* cur = h1;
    float* alt = h0;
    for (int hop = 0; hop < HOPS; ++hop) {
        prop128<<<NN, 128, 0, stream>>>(cur, alt, rowptr, csr_src, csr_w, dinv,
                                        (hop == HOPS - 1) ? 1 : 0);
        float* tmp = cur; cur = alt; alt = tmp;
    }

    // z = cur @ Wc + bc
    gemm40<<<(NN + 31) / 32, 256, 0, stream>>>(cur, Wc, bc, z, NN);
    // out = P z
    prop40<<<NN, 64, 0, stream>>>(z, out, rowptr, csr_src, csr_w, dinv);
}

// Round 4
// 1273.605 us; speedup vs baseline: 2.3051x; 2.3051x over previous
//
#include <hip/hip_runtime.h>
#include <hip/hip_bf16.h>

#define NN 50000
#define NE 800000
#define DH 128
#define NCLS 40
#define HOPS 30

typedef unsigned int uint32;
typedef unsigned short ushort16;

// ---------------- graph build ----------------

__global__ void count_deg(const int* __restrict__ dst, int* __restrict__ cnt) {
    int e = blockIdx.x * blockDim.x + threadIdx.x;
    if (e < NE) atomicAdd(&cnt[dst[e]], 1);
}

__global__ void calc_dinv(const int* __restrict__ cnt, float* __restrict__ dinv) {
    int v = blockIdx.x * blockDim.x + threadIdx.x;
    if (v < NN) dinv[v] = rsqrtf((float)cnt[v] + 1.0f);  // +1 self-loop
}

__global__ void scan1(const int* __restrict__ cnt, int* __restrict__ rowptr,
                      int* __restrict__ bsum) {
    __shared__ int s[1024];
    int t = threadIdx.x;
    int i = blockIdx.x * 1024 + t;
    int v = (i < NN) ? cnt[i] : 0;
    s[t] = v;
    __syncthreads();
    for (int off = 1; off < 1024; off <<= 1) {
        int add = (t >= off) ? s[t - off] : 0;
        __syncthreads();
        s[t] += add;
        __syncthreads();
    }
    if (i < NN) rowptr[i] = s[t] - v;
    if (t == 1023) bsum[blockIdx.x] = s[1023];
}

__global__ void scan2(int* __restrict__ bsum, int* __restrict__ rowptr, int nb) {
    if (blockIdx.x == 0 && threadIdx.x == 0) {
        int run = 0;
        for (int b = 0; b < nb; ++b) { int v = bsum[b]; bsum[b] = run; run += v; }
        rowptr[NN] = run;
    }
}

__global__ void scan3(int* __restrict__ rowptr, const int* __restrict__ bsum,
                      int* __restrict__ cursor) {
    int i = blockIdx.x * 1024 + threadIdx.x;
    if (i < NN) {
        int r = rowptr[i] + bsum[blockIdx.x];
        rowptr[i] = r;
        cursor[i] = r;
    }
}

// csr packed: .x = src node, .y = weight bits
__global__ void fill_csr(const int* __restrict__ src, const int* __restrict__ dst,
                         const float* __restrict__ dinv, int* __restrict__ cursor,
                         int2* __restrict__ csr) {
    int e = blockIdx.x * blockDim.x + threadIdx.x;
    if (e < NE) {
        int s = src[e], d = dst[e];
        int p = atomicAdd(&cursor[d], 1);
        float w = dinv[s] * dinv[d];
        csr[p] = make_int2(s, __float_as_int(w));
    }
}

// ---------------- bf16 helpers ----------------

__device__ __forceinline__ void unpack8(uint4 u, float* f) {
    f[0] = __uint_as_float(u.x << 16);
    f[1] = __uint_as_float(u.x & 0xffff0000u);
    f[2] = __uint_as_float(u.y << 16);
    f[3] = __uint_as_float(u.y & 0xffff0000u);
    f[4] = __uint_as_float(u.z << 16);
    f[5] = __uint_as_float(u.z & 0xffff0000u);
    f[6] = __uint_as_float(u.w << 16);
    f[7] = __uint_as_float(u.w & 0xffff0000u);
}

__device__ __forceinline__ ushort16 f2bf(float x) {
    __hip_bfloat16 b = __float2bfloat16(x);
    return *reinterpret_cast<ushort16*>(&b);
}

// ---------------- GEMMs (f32 vector ALU; no fp32 MFMA on CDNA4) ----------------

// C[n x 128] = relu?(A[n x 128] @ W[128 x 128] + bias); optional bf16 output
template <bool RELU, bool BF16OUT>
__global__ __launch_bounds__(256) void gemm128(const float* __restrict__ A,
                                               const float* __restrict__ W,
                                               const float* __restrict__ bias,
                                               void* __restrict__ C, int n) {
    __shared__ float xs[64 * 128];   // 32 KB
    __shared__ float ws[32 * 128];   // 16 KB
    const int t = threadIdx.x;
    const int row0 = blockIdx.x * 64;

    const float4* A4 = reinterpret_cast<const float4*>(A);
    float4* xs4 = reinterpret_cast<float4*>(xs);
    for (int i = t; i < 64 * 32; i += 256) {
        int r = i >> 5, c4 = i & 31;
        int gr = row0 + r;
        xs4[i] = (gr < n) ? A4[(size_t)gr * 32 + c4] : make_float4(0.f, 0.f, 0.f, 0.f);
    }

    float acc[8][4];
#pragma unroll
    for (int r = 0; r < 8; ++r)
#pragma unroll
        for (int j = 0; j < 4; ++j) acc[r][j] = 0.f;

    const int cb = (t & 31) * 4;
    const int rb = (t >> 5) * 8;
    const float4* W4 = reinterpret_cast<const float4*>(W);
    float4* ws4 = reinterpret_cast<float4*>(ws);

    for (int k0 = 0; k0 < 128; k0 += 32) {
        __syncthreads();
        for (int i = t; i < 32 * 32; i += 256)
            ws4[i] = W4[(size_t)(k0 + (i >> 5)) * 32 + (i & 31)];
        __syncthreads();
#pragma unroll
        for (int kk = 0; kk < 32; ++kk) {
            float4 wv = ws4[kk * 32 + (cb >> 2)];
#pragma unroll
            for (int r = 0; r < 8; ++r) {
                float xv = xs[(rb + r) * 128 + k0 + kk];
                acc[r][0] += xv * wv.x;
                acc[r][1] += xv * wv.y;
                acc[r][2] += xv * wv.z;
                acc[r][3] += xv * wv.w;
            }
        }
    }

    float4 bv = reinterpret_cast<const float4*>(bias)[cb >> 2];
#pragma unroll
    for (int r = 0; r < 8; ++r) {
        int gr = row0 + rb + r;
        if (gr < n) {
            float o[4];
            o[0] = acc[r][0] + bv.x;
            o[1] = acc[r][1] + bv.y;
            o[2] = acc[r][2] + bv.z;
            o[3] = acc[r][3] + bv.w;
            if (RELU) {
#pragma unroll
                for (int j = 0; j < 4; ++j) o[j] = fmaxf(o[j], 0.f);
            }
            if (BF16OUT) {
                ushort16 pk[4];
#pragma unroll
                for (int j = 0; j < 4; ++j) pk[j] = f2bf(o[j]);
                *reinterpret_cast<ushort4*>(reinterpret_cast<ushort16*>(C) +
                                            (size_t)gr * 128 + cb) =
                    *reinterpret_cast<ushort4*>(pk);
            } else {
                float4 ov = make_float4(o[0], o[1], o[2], o[3]);
                reinterpret_cast<float4*>(C)[(size_t)gr * 32 + (cb >> 2)] = ov;
            }
        }
    }
}

// C[n x 40] = A_bf16[n x 128] @ W[128 x 40] + bias  (f32 out)
__global__ __launch_bounds__(256) void gemm40_bf(const uint4* __restrict__ A,
                                                 const float* __restrict__ W,
                                                 const float* __restrict__ bias,
                                                 float* __restrict__ C, int n) {
    __shared__ float xs[32 * 128];   // 16 KB
    __shared__ float wl[128 * 40];   // 20 KB
    __shared__ float bl[40];
    const int t = threadIdx.x;
    const int row0 = blockIdx.x * 32;

    for (int i = t; i < 32 * 16; i += 256) {
        int r = i >> 4, c = i & 15, gr = row0 + r;
        uint4 u = (gr < n) ? A[(size_t)gr * 16 + c] : make_uint4(0, 0, 0, 0);
        float f[8];
        unpack8(u, f);
#pragma unroll
        for (int j = 0; j < 8; ++j) xs[r * 128 + c * 8 + j] = f[j];
    }
    for (int i = t; i < 128 * 40; i += 256) wl[i] = W[i];
    if (t < 40) bl[t] = bias[t];
    __syncthreads();

    const int r = t >> 3;
    const int c0 = (t & 7) * 5;
    float acc[5] = {0.f, 0.f, 0.f, 0.f, 0.f};
    for (int k = 0; k < 128; ++k) {
        float xv = xs[r * 128 + k];
#pragma unroll
        for (int j = 0; j < 5; ++j) acc[j] += xv * wl[k * 40 + c0 + j];
    }
    int gr = row0 + r;
    if (gr < n) {
#pragma unroll
        for (int j = 0; j < 5; ++j) C[(size_t)gr * 40 + c0 + j] = acc[j] + bl[c0 + j];
    }
}

// ---------------- propagation (bf16 h, f32 accum) ----------------
// one node per 16-lane group; each lane owns 8 features (16 B per gather)

__global__ __launch_bounds__(256) void prop_bf(const uint4* __restrict__ hin,
                                               uint4* __restrict__ hout,
                                               const int* __restrict__ rowptr,
                                               const int2* __restrict__ csr,
                                               const float* __restrict__ dinv,
                                               int relu) {
    const int g = threadIdx.x >> 4;
    const int l = threadIdx.x & 15;
    const int v = blockIdx.x * 16 + g;
    if (v >= NN) return;

    const float dv = dinv[v];
    const float wself = dv * dv;

    float acc[8];
    {
        float f[8];
        unpack8(hin[(size_t)v * 16 + l], f);
#pragma unroll
        for (int j = 0; j < 8; ++j) acc[j] = wself * f[j];
    }

    int e = rowptr[v];
    const int end = rowptr[v + 1];
    for (; e + 2 <= end; e += 2) {
        int2 p0 = csr[e];
        int2 p1 = csr[e + 1];
        uint4 a = hin[(size_t)p0.x * 16 + l];
        uint4 b = hin[(size_t)p1.x * 16 + l];
        float w0 = __int_as_float(p0.y);
        float w1 = __int_as_float(p1.y);
        float fa[8], fb[8];
        unpack8(a, fa);
        unpack8(b, fb);
#pragma unroll
        for (int j = 0; j < 8; ++j) acc[j] += w0 * fa[j] + w1 * fb[j];
    }
    if (e < end) {
        int2 p0 = csr[e];
        uint4 a = hin[(size_t)p0.x * 16 + l];
        float w0 = __int_as_float(p0.y);
        float fa[8];
        unpack8(a, fa);
#pragma unroll
        for (int j = 0; j < 8; ++j) acc[j] += w0 * fa[j];
    }

    if (relu) {
#pragma unroll
        for (int j = 0; j < 8; ++j) acc[j] = fmaxf(acc[j], 0.f);
    }

    ushort16 pk[8];
#pragma unroll
    for (int j = 0; j < 8; ++j) pk[j] = f2bf(acc[j]);
    hout[(size_t)v * 16 + l] = *reinterpret_cast<uint4*>(pk);
}

// final hop on D=40 logits (f32)
__global__ __launch_bounds__(64) void prop40(const float* __restrict__ z,
                                             float* __restrict__ out,
                                             const int* __restrict__ rowptr,
                                             const int2* __restrict__ csr,
                                             const float* __restrict__ dinv) {
    const int v = blockIdx.x;
    const int d = threadIdx.x;
    if (d >= NCLS) return;
    float dv = dinv[v];
    float acc = dv * dv * z[(size_t)v * NCLS + d];
    const int beg = rowptr[v], end = rowptr[v + 1];
    for (int e = beg; e < end; ++e) {
        int2 p = csr[e];
        acc += __int_as_float(p.y) * z[(size_t)p.x * NCLS + d];
    }
    out[(size_t)v * NCLS + d] = acc;
}

// ---------------- launch ----------------

extern "C" void kernel_launch(void* const* d_in, const int* in_sizes, int n_in,
                              void* d_out, int out_size, void* d_ws, size_t ws_size,
                              hipStream_t stream) {
    const float* x   = (const float*)d_in[0];
    const int* edge  = (const int*)d_in[1];
    const float* W1  = (const float*)d_in[2];
    const float* b1  = (const float*)d_in[3];
    const float* W2  = (const float*)d_in[4];
    const float* b2  = (const float*)d_in[5];
    const float* Wc  = (const float*)d_in[6];
    const float* bc  = (const float*)d_in[7];
    // d_in[8] = conv_time (=30), hardcoded as HOPS
    const int* esrc = edge;
    const int* edst = edge + NE;
    float* out = (float*)d_out;

    char* w = (char*)d_ws;
    auto alloc = [&](size_t bytes) { void* p = (void*)w; w += (bytes + 255) & ~(size_t)255; return p; };
    int*   cnt    = (int*)  alloc((size_t)NN * 4);
    float* dinv   = (float*)alloc((size_t)NN * 4);
    int*   rowptr = (int*)  alloc((size_t)(NN + 1) * 4);
    int*   bsum   = (int*)  alloc(64 * 4);
    int*   cursor = (int*)  alloc((size_t)NN * 4);
    int2*  csr    = (int2*) alloc((size_t)NE * 8);
    float* h0f    = (float*)alloc((size_t)NN * DH * 4);   // conv1 out (f32)
    uint4* hb0    = (uint4*)alloc((size_t)NN * DH * 2);   // bf16 hop buffers
    uint4* hb1    = (uint4*)alloc((size_t)NN * DH * 2);
    float* z      = (float*)alloc((size_t)NN * NCLS * 4);

    const int NB_SCAN = (NN + 1023) / 1024;  // 49

    hipMemsetAsync(cnt, 0, (size_t)NN * 4, stream);
    count_deg<<<(NE + 255) / 256, 256, 0, stream>>>(edst, cnt);
    calc_dinv<<<(NN + 255) / 256, 256, 0, stream>>>(cnt, dinv);
    scan1<<<NB_SCAN, 1024, 0, stream>>>(cnt, rowptr, bsum);
    scan2<<<1, 64, 0, stream>>>(bsum, rowptr, NB_SCAN);
    scan3<<<NB_SCAN, 1024, 0, stream>>>(rowptr, bsum, cursor);
    fill_csr<<<(NE + 255) / 256, 256, 0, stream>>>(esrc, edst, dinv, cursor, csr);

    // h0f = relu(x @ W1 + b1)   (f32)
    gemm128<true, false><<<(NN + 63) / 64, 256, 0, stream>>>(x, W1, b1, h0f, NN);
    // hb0 = bf16(h0f @ W2 + b2)
    gemm128<false, true><<<(NN + 63) / 64, 256, 0, stream>>>(h0f, W2, b2, hb0, NN);

    // 30 propagation hops in bf16; relu on the last
    uint4* cur = hb0;
    uint4* alt = hb1;
    for (int hop = 0; hop < HOPS; ++hop) {
        prop_bf<<<(NN + 15) / 16, 256, 0, stream>>>(cur, alt, rowptr, csr, dinv,
                                                    (hop == HOPS - 1) ? 1 : 0);
        uint4* tmp = cur; cur = alt; alt = tmp;
    }

    // z = cur @ Wc + bc
    gemm40_bf<<<(NN + 31) / 32, 256, 0, stream>>>(cur, Wc, bc, z, NN);
    // out = P z
    prop40<<<NN, 64, 0, stream>>>(z, out, rowptr, csr, dinv);
}